// Round 1
// baseline (445.966 us; speedup 1.0000x reference)
//
#include <hip/hip_runtime.h>
#include <hip/hip_bf16.h>

// TVHMM forward log-likelihood, chunk-parallel linear-domain operator scan.
// ws layout (bytes), total required ~74.2 MB:
//   0x0000000 emp    [8192][64] f32   em'_t(j) = exp(log_em - c_t)
//   0x0200000 cvec   [8192] f32       c_t = max_j log_em[t][j]
//   0x0210000 muT    [64][64] f32     mu transposed
//   0x0214000 ivT    [64][64] f32     exp(-clip(logvar)) transposed
//   0x0218000 logdet [64] f32
//   0x0400000 Ap     [8192][64][64] bf16  A'_t = softmax(logits_t) * diag(em'_t)
//   0x4400000 Mc     [256][64][64] bf16   chunk products (32 steps each)
//   0x4600000 sc1    [256][4] f32         per-16-row-block log scales
//   0x4601000 M2     [64][64][64] bf16
//   0x4681000 sc2    [64][4] f32
//   0x4682000 M3     [16][64][64] bf16
//   0x46A2000 sc3    [16][4] f32
//   0x46A3000 M4     [4][64][64] bf16
//   0x46AB000 sc4    [4][4] f32

typedef unsigned int u32;
typedef unsigned short u16;

#define T_LEN 8192

__device__ __forceinline__ float bflo(u32 u){ return __uint_as_float(u << 16); }
__device__ __forceinline__ float bfhi(u32 u){ return __uint_as_float(u & 0xffff0000u); }
// f32 -> bf16 round-to-nearest-even (values are positive finite here)
__device__ __forceinline__ u32 f2bf(float x){
  u32 b = __float_as_uint(x);
  return (b + 0x7fffu + ((b >> 16) & 1u)) >> 16;
}
__device__ __forceinline__ u32 pack2bf(float a, float b){
  return f2bf(a) | (f2bf(b) << 16);
}

// ---------------------------------------------------------------- k_prep
__global__ __launch_bounds__(64) void k_prep(
    const float* __restrict__ mu, const float* __restrict__ lvu,
    float* __restrict__ muT, float* __restrict__ ivT, float* __restrict__ logdet)
{
  const int k = threadIdx.x;   // state 0..63
  float ld = 0.f;
  for (int d = 0; d < 64; ++d){
    float lv = fminf(fmaxf(lvu[k*64 + d], -6.f), 6.f);
    ld += lv;
    muT[d*64 + k] = mu[k*64 + d];
    ivT[d*64 + k] = __expf(-lv);
  }
  logdet[k] = ld;
}

// ---------------------------------------------------------------- k_emis
// one wave per t: lane k computes log_em[t][k]; store em' and c_t
__global__ __launch_bounds__(256) void k_emis(
    const float* __restrict__ Y, const float* __restrict__ muT,
    const float* __restrict__ ivT, const float* __restrict__ logdet,
    float* __restrict__ emp, float* __restrict__ cvec)
{
  const int w = threadIdx.x >> 6, k = threadIdx.x & 63;
  const int t = blockIdx.x * 4 + w;
  float y = Y[(size_t)t*64 + k];      // lane k holds Y[t][k]
  float quad = 0.f;
  #pragma unroll 8
  for (int d = 0; d < 64; ++d){
    float yd = __shfl(y, d, 64);      // broadcast Y[t][d]
    float df = yd - muT[d*64 + k];
    quad = fmaf(df*df, ivT[d*64 + k], quad);
  }
  // 64*log(2*pi) = 117.6241322...
  float le = -0.5f*(117.6241322f + logdet[k] + quad);
  float m = le;
  #pragma unroll
  for (int off = 1; off < 64; off <<= 1) m = fmaxf(m, __shfl_xor(m, off, 64));
  emp[(size_t)t*64 + k] = __expf(le - m);
  if (k == 0) cvec[t] = m;
}

// ---------------------------------------------------------------- k_trans
// WG (bt, i): 64 t-rows x all 64 j for one source state i.
// logits = b[i][j] + X[t]·W[i][j][:]; row-softmax over j; * em'[t][j]; bf16 out
__global__ __launch_bounds__(256) void k_trans(
    const float* __restrict__ X, const float* __restrict__ W,
    const float* __restrict__ bmat, const float* __restrict__ emp,
    u16* __restrict__ Ap)
{
  __shared__ float Xs[64][130];     // 33.3 KB, pad vs bank conflicts
  __shared__ u16 WsT[128][68];      // 17.4 KB, W slice transposed, bf16
  const int tid = threadIdx.x;
  const int t0 = blockIdx.x * 64;
  const int i  = blockIdx.y;

  { // stage (coalesced flat reads)
    const float4* xs   = (const float4*)(X + (size_t)t0 * 128);
    const float4* wsrc = (const float4*)(W + (size_t)i * 8192);
    #pragma unroll
    for (int u = 0; u < 8; ++u){
      int fi = tid*8 + u;
      int el = fi * 4;                    // flat element 0..8191
      float4 v = xs[fi];
      float* dx = &Xs[el >> 7][el & 127];
      dx[0]=v.x; dx[1]=v.y; dx[2]=v.z; dx[3]=v.w;
      float4 wv = wsrc[fi];
      int j = el >> 7, d = el & 127;      // W slice flat: j*128 + d
      WsT[d+0][j] = (u16)f2bf(wv.x);
      WsT[d+1][j] = (u16)f2bf(wv.y);
      WsT[d+2][j] = (u16)f2bf(wv.z);
      WsT[d+3][j] = (u16)f2bf(wv.w);
    }
  }
  __syncthreads();

  const int tx = tid & 15, ty = tid >> 4;   // cols 4tx.., rows 4ty..
  float acc[4][4];
  #pragma unroll
  for (int a = 0; a < 4; ++a)
    #pragma unroll
    for (int b = 0; b < 4; ++b) acc[a][b] = 0.f;

  #pragma unroll 4
  for (int d = 0; d < 128; ++d){
    uint2 wp = *(const uint2*)&WsT[d][tx*4];
    float w0 = bflo(wp.x), w1 = bfhi(wp.x), w2 = bflo(wp.y), w3 = bfhi(wp.y);
    #pragma unroll
    for (int rr = 0; rr < 4; ++rr){
      float xa = Xs[ty*4 + rr][d];
      acc[rr][0] = fmaf(xa, w0, acc[rr][0]);
      acc[rr][1] = fmaf(xa, w1, acc[rr][1]);
      acc[rr][2] = fmaf(xa, w2, acc[rr][2]);
      acc[rr][3] = fmaf(xa, w3, acc[rr][3]);
    }
  }

  const float b0 = bmat[i*64 + tx*4 + 0];
  const float b1 = bmat[i*64 + tx*4 + 1];
  const float b2 = bmat[i*64 + tx*4 + 2];
  const float b3 = bmat[i*64 + tx*4 + 3];

  #pragma unroll
  for (int rr = 0; rr < 4; ++rr){
    const int t = t0 + ty*4 + rr;
    float v0 = acc[rr][0] + b0, v1 = acc[rr][1] + b1;
    float v2 = acc[rr][2] + b2, v3 = acc[rr][3] + b3;
    float mx = fmaxf(fmaxf(v0,v1), fmaxf(v2,v3));
    #pragma unroll
    for (int off = 1; off < 16; off <<= 1) mx = fmaxf(mx, __shfl_xor(mx, off, 64));
    float e0 = __expf(v0-mx), e1 = __expf(v1-mx), e2 = __expf(v2-mx), e3 = __expf(v3-mx);
    float sum = e0 + e1 + e2 + e3;
    #pragma unroll
    for (int off = 1; off < 16; off <<= 1) sum += __shfl_xor(sum, off, 64);
    float inv = 1.0f / sum;
    const float* er = emp + (size_t)t*64 + tx*4;
    u32 o0 = pack2bf(e0*inv*er[0], e1*inv*er[1]);
    u32 o1 = pack2bf(e2*inv*er[2], e3*inv*er[3]);
    *(uint2*)(Ap + (size_t)t*4096 + i*64 + tx*4) = make_uint2(o0, o1);
  }
}

// ---------------------------------------------------------------- k_scan
// Fold `cnt` consecutive 64x64 bf16 matrices (stride 4096 elems) into one:
// M <- rescale(M * Op_k). State in registers: wave w owns rows 16w..16w+15;
// lane (r,g) holds row 16w+r, cols 16g..16g+15 as 8 col-pair-packed u32.
// Operand staged in LDS as row-pair-packed u32, XOR-swizzled, double-buffered.
// Per-wave (16-row-block) log scales in/out. Used for stage C and combine levels.
__global__ __launch_bounds__(256) void k_scan(
    const u16* __restrict__ mats, int per_wg, int skip0,
    const float* __restrict__ in_sc,
    u16* __restrict__ out_m, float* __restrict__ out_sc)
{
  __shared__ u32 Apk[2][32][64];   // [buf][row-pair p][16 chunks x 4 u32] 16 KB
  const int tid = threadIdx.x;
  const int lane = tid & 63, w = tid >> 6;
  const int r = lane & 15, g = lane >> 4;
  int c0 = blockIdx.x * per_wg, cnt = per_wg;
  if (blockIdx.x == 0){ c0 += skip0; cnt -= skip0; }

  u32 M[8];
  { // init: M = mats[c0] (row-major bf16 pairs are exactly col-pair packing)
    const uint4* mp0 = (const uint4*)(mats + ((size_t)c0 << 12) + ((w*16 + r) << 6) + (g << 4));
    uint4 a = mp0[0], b = mp0[1];
    M[0]=a.x; M[1]=a.y; M[2]=a.z; M[3]=a.w;
    M[4]=b.x; M[5]=b.y; M[6]=b.z; M[7]=b.w;
  }
  float S = in_sc ? in_sc[c0*4 + w] : 0.0f;

  const int lp = tid >> 3, c8 = tid & 7;   // staging: row-pair lp, col-oct c8
  auto STAGE = [&](int buf, const u16* src){
    const uint4 A = *(const uint4*)(src + lp*128 + c8*8);        // row 2lp
    const uint4 B = *(const uint4*)(src + lp*128 + 64 + c8*8);   // row 2lp+1
    uint4 o0, o1;
    o0.x = (A.x & 0xffffu) | (B.x << 16);
    o0.y = (A.x >> 16)     | (B.x & 0xffff0000u);
    o0.z = (A.y & 0xffffu) | (B.y << 16);
    o0.w = (A.y >> 16)     | (B.y & 0xffff0000u);
    o1.x = (A.z & 0xffffu) | (B.z << 16);
    o1.y = (A.z >> 16)     | (B.z & 0xffff0000u);
    o1.z = (A.w & 0xffffu) | (B.w << 16);
    o1.w = (A.w >> 16)     | (B.w & 0xffff0000u);
    const int s = lp & 7;  // chunk-granular XOR swizzle (bank spread)
    *(uint4*)&Apk[buf][lp][((2*c8    ) ^ s) << 2] = o0;
    *(uint4*)&Apk[buf][lp][((2*c8 + 1) ^ s) << 2] = o1;
  };

  if (cnt > 1) STAGE(0, mats + ((size_t)(c0+1) << 12));
  __syncthreads();
  int cur = 0;
  for (int kk = 1; kk < cnt; ++kk){
    if (kk + 1 < cnt) STAGE(cur ^ 1, mats + ((size_t)(c0 + kk + 1) << 12));

    if (in_sc){ // fold input row-block scales of Op into M's columns
      const float* sp = in_sc + (size_t)(c0 + kk)*4;
      float s0=sp[0], s1=sp[1], s2=sp[2], s3=sp[3];
      float sm = fmaxf(fmaxf(s0,s1), fmaxf(s2,s3));
      float se = __expf(sp[g] - sm);
      S += sm;
      #pragma unroll
      for (int q = 0; q < 8; ++q)
        M[q] = pack2bf(bflo(M[q])*se, bfhi(M[q])*se);
    }

    float acc[16];
    #pragma unroll
    for (int c = 0; c < 16; ++c) acc[c] = 0.f;
    const u32* Ab = &Apk[cur][0][0];
    #pragma unroll
    for (int p = 0; p < 32; ++p){
      u32 mp = __shfl(M[p & 7], r + ((p >> 3) << 4), 64);  // M[row][2p],[2p+1]
      float m0 = bflo(mp), m1 = bfhi(mp);
      const u32* Ar = Ab + p*64;
      #pragma unroll
      for (int k4 = 0; k4 < 4; ++k4){
        uint4 av = *(const uint4*)(Ar + ((((g<<2) + k4) ^ (p & 7)) << 2));
        acc[k4*4+0] = fmaf(m1, bfhi(av.x), fmaf(m0, bflo(av.x), acc[k4*4+0]));
        acc[k4*4+1] = fmaf(m1, bfhi(av.y), fmaf(m0, bflo(av.y), acc[k4*4+1]));
        acc[k4*4+2] = fmaf(m1, bfhi(av.z), fmaf(m0, bflo(av.z), acc[k4*4+2]));
        acc[k4*4+3] = fmaf(m1, bfhi(av.w), fmaf(m0, bflo(av.w), acc[k4*4+3]));
      }
    }
    // per-wave rescale (wave == one 16-row block)
    float mx = acc[0];
    #pragma unroll
    for (int c = 1; c < 16; ++c) mx = fmaxf(mx, acc[c]);
    #pragma unroll
    for (int off = 1; off < 64; off <<= 1) mx = fmaxf(mx, __shfl_xor(mx, off, 64));
    float inv = 1.0f / mx;
    S += __logf(mx);
    #pragma unroll
    for (int q = 0; q < 8; ++q)
      M[q] = pack2bf(acc[2*q]*inv, acc[2*q+1]*inv);
    cur ^= 1;
    __syncthreads();
  }
  {
    uint4* outp = (uint4*)(out_m + ((size_t)blockIdx.x << 12) + ((w*16 + r) << 6) + (g << 4));
    uint4 a, b;
    a.x=M[0]; a.y=M[1]; a.z=M[2]; a.w=M[3];
    b.x=M[4]; b.y=M[5]; b.z=M[6]; b.w=M[7];
    outp[0] = a; outp[1] = b;
    if (lane == 0) out_sc[blockIdx.x*4 + w] = S;
  }
}

// ---------------------------------------------------------------- k_final
// csum = sum c_t; alpha = pi0 .* em'_0; alpha <- alpha*M4[d] (rescaled);
// out = log(sum alpha) + all scales
__global__ __launch_bounds__(256) void k_final(
    const float* __restrict__ init_logits, const float* __restrict__ emp,
    const float* __restrict__ cvec, const u16* __restrict__ Mfin,
    const float* __restrict__ scfin, int nmat, float* __restrict__ out)
{
  __shared__ float wsum[4];
  const int tid = threadIdx.x;
  float part = 0.f;
  for (int t = tid; t < T_LEN; t += 256) part += cvec[t];
  #pragma unroll
  for (int off = 1; off < 64; off <<= 1) part += __shfl_xor(part, off, 64);
  if ((tid & 63) == 0) wsum[tid >> 6] = part;
  __syncthreads();
  if (tid >= 64) return;
  const float csum = wsum[0] + wsum[1] + wsum[2] + wsum[3];
  const int k = tid;
  float ilv = init_logits[k];
  float m = ilv;
  #pragma unroll
  for (int off = 1; off < 64; off <<= 1) m = fmaxf(m, __shfl_xor(m, off, 64));
  float e = __expf(ilv - m);
  float s = e;
  #pragma unroll
  for (int off = 1; off < 64; off <<= 1) s += __shfl_xor(s, off, 64);
  float alpha = (e / s) * emp[k];   // pi0_k * em'_0(k)
  float S = 0.f;
  for (int d = 0; d < nmat; ++d){
    const float* sp = scfin + d*4;
    float sm = fmaxf(fmaxf(sp[0], sp[1]), fmaxf(sp[2], sp[3]));
    alpha *= __expf(sp[k >> 4] - sm);   // fold matrix-row-block scales into alpha
    S += sm;
    const u16* Mp = Mfin + ((size_t)d << 12);
    float an = 0.f;
    for (int i2 = 0; i2 < 64; ++i2){
      float av = __shfl(alpha, i2, 64);
      an = fmaf(av, __uint_as_float(((u32)Mp[i2*64 + k]) << 16), an);
    }
    float mx = an;
    #pragma unroll
    for (int off = 1; off < 64; off <<= 1) mx = fmaxf(mx, __shfl_xor(mx, off, 64));
    alpha = an / mx;
    S += __logf(mx);
  }
  float tot = alpha;
  #pragma unroll
  for (int off = 1; off < 64; off <<= 1) tot += __shfl_xor(tot, off, 64);
  if (k == 0) out[0] = __logf(tot) + S + csum;
}

// ---------------------------------------------------------------- launch
extern "C" void kernel_launch(void* const* d_in, const int* in_sizes, int n_in,
                              void* d_out, int out_size, void* d_ws, size_t ws_size,
                              hipStream_t stream)
{
  const float* X  = (const float*)d_in[0];
  const float* Y  = (const float*)d_in[1];
  const float* il = (const float*)d_in[2];
  const float* W  = (const float*)d_in[3];
  const float* bm = (const float*)d_in[4];
  const float* mu = (const float*)d_in[5];
  const float* lv = (const float*)d_in[6];
  float* out = (float*)d_out;
  char* ws = (char*)d_ws;
  (void)in_sizes; (void)n_in; (void)out_size; (void)ws_size; // need ~74.2 MB ws

  float* emp    = (float*)(ws + 0x0000000);
  float* cvec   = (float*)(ws + 0x0200000);
  float* muT    = (float*)(ws + 0x0210000);
  float* ivT    = (float*)(ws + 0x0214000);
  float* logdet = (float*)(ws + 0x0218000);
  u16*   Ap     = (u16*)  (ws + 0x0400000);
  u16*   Mc     = (u16*)  (ws + 0x4400000);
  float* sc1    = (float*)(ws + 0x4600000);
  u16*   M2     = (u16*)  (ws + 0x4601000);
  float* sc2    = (float*)(ws + 0x4681000);
  u16*   M3     = (u16*)  (ws + 0x4682000);
  float* sc3    = (float*)(ws + 0x46A2000);
  u16*   M4     = (u16*)  (ws + 0x46A3000);
  float* sc4    = (float*)(ws + 0x46AB000);

  k_prep <<<1, 64, 0, stream>>>(mu, lv, muT, ivT, logdet);
  k_emis <<<2048, 256, 0, stream>>>(Y, muT, ivT, logdet, emp, cvec);
  k_trans<<<dim3(128, 64), 256, 0, stream>>>(X, W, bm, emp, Ap);
  // stage C: 256 chunks x 32 matrices (chunk 0 skips t=0; em_0 enters via alpha0)
  k_scan <<<256, 256, 0, stream>>>(Ap, 32, 1, (const float*)nullptr, Mc, sc1);
  // combine levels, fan-in 4: 256 -> 64 -> 16 -> 4
  k_scan <<<64, 256, 0, stream>>>(Mc, 4, 0, sc1, M2, sc2);
  k_scan <<<16, 256, 0, stream>>>(M2, 4, 0, sc2, M3, sc3);
  k_scan <<<4,  256, 0, stream>>>(M3, 4, 0, sc3, M4, sc4);
  k_final<<<1, 256, 0, stream>>>(il, emp, cvec, M4, sc4, 4, out);
}

// Round 2
// 339.674 us; speedup vs baseline: 1.3129x; 1.3129x over previous
//
#include <hip/hip_runtime.h>
#include <hip/hip_bf16.h>

// TVHMM forward log-likelihood, chunk-parallel linear-domain operator scan.
// R1: k_trans rewritten as bf16 MFMA (16x16x32), XOR-swizzled LDS staging.
// ws layout (bytes), total required ~74.2 MB (unchanged).

typedef unsigned int u32;
typedef unsigned short u16;

#define T_LEN 8192

typedef __attribute__((ext_vector_type(8))) short bf16x8;
typedef __attribute__((ext_vector_type(4))) float f32x4;

__device__ __forceinline__ float bflo(u32 u){ return __uint_as_float(u << 16); }
__device__ __forceinline__ float bfhi(u32 u){ return __uint_as_float(u & 0xffff0000u); }
// f32 -> bf16 round-to-nearest-even (finite values)
__device__ __forceinline__ u32 f2bf(float x){
  u32 b = __float_as_uint(x);
  return (b + 0x7fffu + ((b >> 16) & 1u)) >> 16;
}
__device__ __forceinline__ u32 pack2bf(float a, float b){
  return f2bf(a) | (f2bf(b) << 16);
}

// ---------------------------------------------------------------- k_prep
__global__ __launch_bounds__(64) void k_prep(
    const float* __restrict__ mu, const float* __restrict__ lvu,
    float* __restrict__ muT, float* __restrict__ ivT, float* __restrict__ logdet)
{
  const int k = threadIdx.x;   // state 0..63
  float ld = 0.f;
  for (int d = 0; d < 64; ++d){
    float lv = fminf(fmaxf(lvu[k*64 + d], -6.f), 6.f);
    ld += lv;
    muT[d*64 + k] = mu[k*64 + d];
    ivT[d*64 + k] = __expf(-lv);
  }
  logdet[k] = ld;
}

// ---------------------------------------------------------------- k_emis
// one wave per t: lane k computes log_em[t][k]; store em' and c_t
__global__ __launch_bounds__(256) void k_emis(
    const float* __restrict__ Y, const float* __restrict__ muT,
    const float* __restrict__ ivT, const float* __restrict__ logdet,
    float* __restrict__ emp, float* __restrict__ cvec)
{
  const int w = threadIdx.x >> 6, k = threadIdx.x & 63;
  const int t = blockIdx.x * 4 + w;
  float y = Y[(size_t)t*64 + k];      // lane k holds Y[t][k]
  float quad = 0.f;
  #pragma unroll 8
  for (int d = 0; d < 64; ++d){
    float yd = __shfl(y, d, 64);      // broadcast Y[t][d]
    float df = yd - muT[d*64 + k];
    quad = fmaf(df*df, ivT[d*64 + k], quad);
  }
  // 64*log(2*pi) = 117.6241322...
  float le = -0.5f*(117.6241322f + logdet[k] + quad);
  float m = le;
  #pragma unroll
  for (int off = 1; off < 64; off <<= 1) m = fmaxf(m, __shfl_xor(m, off, 64));
  emp[(size_t)t*64 + k] = __expf(le - m);
  if (k == 0) cvec[t] = m;
}

// ---------------------------------------------------------------- k_trans (MFMA)
// Block (bt, i): 128 t-rows x 64 j-cols for source state i.
// logits = b[i][j] + X[t]·W[i][j][:]; row-softmax over j; * em'[t][j]; bf16 out.
// A = X tile (bf16, LDS swizzled), B = W[i] slice (bf16, LDS swizzled).
// 4 waves: wave w owns t-rows w*32..w*32+31 (2 m-tiles), all 64 j (4 n-tiles).
__global__ __launch_bounds__(256) void k_trans(
    const float* __restrict__ X, const float* __restrict__ W,
    const float* __restrict__ bmat, const float* __restrict__ emp,
    u16* __restrict__ Ap)
{
  __shared__ __align__(16) u16 Xs[128*128];   // 32 KB, XOR-swizzled rows
  __shared__ __align__(16) u16 Ws[64*128];    // 16 KB
  const int tid = threadIdx.x;
  const int t0 = blockIdx.x * 128;
  const int i  = blockIdx.y;

  { // stage X: 4096 float4 -> bf16 ds_write_b64, swizzle byte ^= (row&7)<<4
    const float4* xs = (const float4*)(X + (size_t)t0 * 128);
    #pragma unroll
    for (int u = 0; u < 16; ++u){
      int f = u*256 + tid;                 // float4 index; lanes coalesced
      float4 v = xs[f];
      int row = f >> 5, c = f & 31;        // 32 float4 per 128-col row
      int byte = (row*256 + c*8) ^ ((row & 7) << 4);
      *(uint2*)((char*)Xs + byte) = make_uint2(pack2bf(v.x, v.y), pack2bf(v.z, v.w));
    }
    const float4* wsrc = (const float4*)(W + (size_t)i * 8192);
    #pragma unroll
    for (int u = 0; u < 8; ++u){
      int f = u*256 + tid;
      float4 v = wsrc[f];
      int row = f >> 5, c = f & 31;        // row = j (0..63)
      int byte = (row*256 + c*8) ^ ((row & 7) << 4);
      *(uint2*)((char*)Ws + byte) = make_uint2(pack2bf(v.x, v.y), pack2bf(v.z, v.w));
    }
  }
  __syncthreads();

  const int lane = tid & 63, w = tid >> 6;
  const int lr = lane & 15, lg = lane >> 4;

  f32x4 acc[2][4] = {};
  #pragma unroll
  for (int kg = 0; kg < 4; ++kg){          // K = 128 = 4 x 32
    const int kbyte = kg*64 + lg*16;       // 8 contiguous bf16 at k=kg*32+lg*8
    bf16x8 a[2], b[4];
    #pragma unroll
    for (int mt = 0; mt < 2; ++mt){
      int row = w*32 + mt*16 + lr;
      a[mt] = *(const bf16x8*)((const char*)Xs + ((row*256 + kbyte) ^ ((row&7)<<4)));
    }
    #pragma unroll
    for (int nt = 0; nt < 4; ++nt){
      int row = nt*16 + lr;                // row = j in W slice == B column
      b[nt] = *(const bf16x8*)((const char*)Ws + ((row*256 + kbyte) ^ ((row&7)<<4)));
    }
    #pragma unroll
    for (int mt = 0; mt < 2; ++mt)
      #pragma unroll
      for (int nt = 0; nt < 4; ++nt)
        acc[mt][nt] = __builtin_amdgcn_mfma_f32_16x16x32_bf16(a[mt], b[nt], acc[mt][nt], 0, 0, 0);
  }

  // epilogue: +b, softmax over j (4 in-thread + 16-lane group), *emp, store bf16
  float bv[4];
  #pragma unroll
  for (int nt = 0; nt < 4; ++nt) bv[nt] = bmat[i*64 + nt*16 + lr];

  #pragma unroll
  for (int mt = 0; mt < 2; ++mt){
    #pragma unroll
    for (int reg = 0; reg < 4; ++reg){
      const int t = t0 + w*32 + mt*16 + lg*4 + reg;   // C row = lg*4+reg
      float v0 = acc[mt][0][reg] + bv[0];
      float v1 = acc[mt][1][reg] + bv[1];
      float v2 = acc[mt][2][reg] + bv[2];
      float v3 = acc[mt][3][reg] + bv[3];
      float mx = fmaxf(fmaxf(v0,v1), fmaxf(v2,v3));
      #pragma unroll
      for (int off = 1; off < 16; off <<= 1) mx = fmaxf(mx, __shfl_xor(mx, off, 64));
      float e0 = __expf(v0-mx), e1 = __expf(v1-mx), e2 = __expf(v2-mx), e3 = __expf(v3-mx);
      float sum = e0 + e1 + e2 + e3;
      #pragma unroll
      for (int off = 1; off < 16; off <<= 1) sum += __shfl_xor(sum, off, 64);
      float inv = 1.0f / sum;
      const float* er = emp + (size_t)t*64;
      u16* op = Ap + (size_t)t*4096 + i*64;
      op[ 0 + lr] = (u16)f2bf(e0*inv*er[ 0 + lr]);
      op[16 + lr] = (u16)f2bf(e1*inv*er[16 + lr]);
      op[32 + lr] = (u16)f2bf(e2*inv*er[32 + lr]);
      op[48 + lr] = (u16)f2bf(e3*inv*er[48 + lr]);
    }
  }
}

// ---------------------------------------------------------------- k_scan
// Fold `cnt` consecutive 64x64 bf16 matrices (stride 4096 elems) into one:
// M <- rescale(M * Op_k). State in registers: wave w owns rows 16w..16w+15;
// lane (r,g) holds row 16w+r, cols 16g..16g+15 as 8 col-pair-packed u32.
// Operand staged in LDS as row-pair-packed u32, XOR-swizzled, double-buffered.
__global__ __launch_bounds__(256) void k_scan(
    const u16* __restrict__ mats, int per_wg, int skip0,
    const float* __restrict__ in_sc,
    u16* __restrict__ out_m, float* __restrict__ out_sc)
{
  __shared__ u32 Apk[2][32][64];   // [buf][row-pair p][16 chunks x 4 u32] 16 KB
  const int tid = threadIdx.x;
  const int lane = tid & 63, w = tid >> 6;
  const int r = lane & 15, g = lane >> 4;
  int c0 = blockIdx.x * per_wg, cnt = per_wg;
  if (blockIdx.x == 0){ c0 += skip0; cnt -= skip0; }

  u32 M[8];
  { // init: M = mats[c0] (row-major bf16 pairs are exactly col-pair packing)
    const uint4* mp0 = (const uint4*)(mats + ((size_t)c0 << 12) + ((w*16 + r) << 6) + (g << 4));
    uint4 a = mp0[0], b = mp0[1];
    M[0]=a.x; M[1]=a.y; M[2]=a.z; M[3]=a.w;
    M[4]=b.x; M[5]=b.y; M[6]=b.z; M[7]=b.w;
  }
  float S = in_sc ? in_sc[c0*4 + w] : 0.0f;

  const int lp = tid >> 3, c8 = tid & 7;   // staging: row-pair lp, col-oct c8
  auto STAGE = [&](int buf, const u16* src){
    const uint4 A = *(const uint4*)(src + lp*128 + c8*8);        // row 2lp
    const uint4 B = *(const uint4*)(src + lp*128 + 64 + c8*8);   // row 2lp+1
    uint4 o0, o1;
    o0.x = (A.x & 0xffffu) | (B.x << 16);
    o0.y = (A.x >> 16)     | (B.x & 0xffff0000u);
    o0.z = (A.y & 0xffffu) | (B.y << 16);
    o0.w = (A.y >> 16)     | (B.y & 0xffff0000u);
    o1.x = (A.z & 0xffffu) | (B.z << 16);
    o1.y = (A.z >> 16)     | (B.z & 0xffff0000u);
    o1.z = (A.w & 0xffffu) | (B.w << 16);
    o1.w = (A.w >> 16)     | (B.w & 0xffff0000u);
    const int s = lp & 7;  // chunk-granular XOR swizzle (bank spread)
    *(uint4*)&Apk[buf][lp][((2*c8    ) ^ s) << 2] = o0;
    *(uint4*)&Apk[buf][lp][((2*c8 + 1) ^ s) << 2] = o1;
  };

  if (cnt > 1) STAGE(0, mats + ((size_t)(c0+1) << 12));
  __syncthreads();
  int cur = 0;
  for (int kk = 1; kk < cnt; ++kk){
    if (kk + 1 < cnt) STAGE(cur ^ 1, mats + ((size_t)(c0 + kk + 1) << 12));

    if (in_sc){ // fold input row-block scales of Op into M's columns
      const float* sp = in_sc + (size_t)(c0 + kk)*4;
      float s0=sp[0], s1=sp[1], s2=sp[2], s3=sp[3];
      float sm = fmaxf(fmaxf(s0,s1), fmaxf(s2,s3));
      float se = __expf(sp[g] - sm);
      S += sm;
      #pragma unroll
      for (int q = 0; q < 8; ++q)
        M[q] = pack2bf(bflo(M[q])*se, bfhi(M[q])*se);
    }

    float acc[16];
    #pragma unroll
    for (int c = 0; c < 16; ++c) acc[c] = 0.f;
    const u32* Ab = &Apk[cur][0][0];
    #pragma unroll
    for (int p = 0; p < 32; ++p){
      u32 mp = __shfl(M[p & 7], r + ((p >> 3) << 4), 64);  // M[row][2p],[2p+1]
      float m0 = bflo(mp), m1 = bfhi(mp);
      const u32* Ar = Ab + p*64;
      #pragma unroll
      for (int k4 = 0; k4 < 4; ++k4){
        uint4 av = *(const uint4*)(Ar + ((((g<<2) + k4) ^ (p & 7)) << 2));
        acc[k4*4+0] = fmaf(m1, bfhi(av.x), fmaf(m0, bflo(av.x), acc[k4*4+0]));
        acc[k4*4+1] = fmaf(m1, bfhi(av.y), fmaf(m0, bflo(av.y), acc[k4*4+1]));
        acc[k4*4+2] = fmaf(m1, bfhi(av.z), fmaf(m0, bflo(av.z), acc[k4*4+2]));
        acc[k4*4+3] = fmaf(m1, bfhi(av.w), fmaf(m0, bflo(av.w), acc[k4*4+3]));
      }
    }
    // per-wave rescale (wave == one 16-row block)
    float mx = acc[0];
    #pragma unroll
    for (int c = 1; c < 16; ++c) mx = fmaxf(mx, acc[c]);
    #pragma unroll
    for (int off = 1; off < 64; off <<= 1) mx = fmaxf(mx, __shfl_xor(mx, off, 64));
    float inv = 1.0f / mx;
    S += __logf(mx);
    #pragma unroll
    for (int q = 0; q < 8; ++q)
      M[q] = pack2bf(acc[2*q]*inv, acc[2*q+1]*inv);
    cur ^= 1;
    __syncthreads();
  }
  {
    uint4* outp = (uint4*)(out_m + ((size_t)blockIdx.x << 12) + ((w*16 + r) << 6) + (g << 4));
    uint4 a, b;
    a.x=M[0]; a.y=M[1]; a.z=M[2]; a.w=M[3];
    b.x=M[4]; b.y=M[5]; b.z=M[6]; b.w=M[7];
    outp[0] = a; outp[1] = b;
    if (lane == 0) out_sc[blockIdx.x*4 + w] = S;
  }
}

// ---------------------------------------------------------------- k_final
__global__ __launch_bounds__(256) void k_final(
    const float* __restrict__ init_logits, const float* __restrict__ emp,
    const float* __restrict__ cvec, const u16* __restrict__ Mfin,
    const float* __restrict__ scfin, int nmat, float* __restrict__ out)
{
  __shared__ float wsum[4];
  const int tid = threadIdx.x;
  float part = 0.f;
  for (int t = tid; t < T_LEN; t += 256) part += cvec[t];
  #pragma unroll
  for (int off = 1; off < 64; off <<= 1) part += __shfl_xor(part, off, 64);
  if ((tid & 63) == 0) wsum[tid >> 6] = part;
  __syncthreads();
  if (tid >= 64) return;
  const float csum = wsum[0] + wsum[1] + wsum[2] + wsum[3];
  const int k = tid;
  float ilv = init_logits[k];
  float m = ilv;
  #pragma unroll
  for (int off = 1; off < 64; off <<= 1) m = fmaxf(m, __shfl_xor(m, off, 64));
  float e = __expf(ilv - m);
  float s = e;
  #pragma unroll
  for (int off = 1; off < 64; off <<= 1) s += __shfl_xor(s, off, 64);
  float alpha = (e / s) * emp[k];   // pi0_k * em'_0(k)
  float S = 0.f;
  for (int d = 0; d < nmat; ++d){
    const float* sp = scfin + d*4;
    float sm = fmaxf(fmaxf(sp[0], sp[1]), fmaxf(sp[2], sp[3]));
    alpha *= __expf(sp[k >> 4] - sm);   // fold matrix-row-block scales into alpha
    S += sm;
    const u16* Mp = Mfin + ((size_t)d << 12);
    float an = 0.f;
    for (int i2 = 0; i2 < 64; ++i2){
      float av = __shfl(alpha, i2, 64);
      an = fmaf(av, __uint_as_float(((u32)Mp[i2*64 + k]) << 16), an);
    }
    float mx = an;
    #pragma unroll
    for (int off = 1; off < 64; off <<= 1) mx = fmaxf(mx, __shfl_xor(mx, off, 64));
    alpha = an / mx;
    S += __logf(mx);
  }
  float tot = alpha;
  #pragma unroll
  for (int off = 1; off < 64; off <<= 1) tot += __shfl_xor(tot, off, 64);
  if (k == 0) out[0] = __logf(tot) + S + csum;
}

// ---------------------------------------------------------------- launch
extern "C" void kernel_launch(void* const* d_in, const int* in_sizes, int n_in,
                              void* d_out, int out_size, void* d_ws, size_t ws_size,
                              hipStream_t stream)
{
  const float* X  = (const float*)d_in[0];
  const float* Y  = (const float*)d_in[1];
  const float* il = (const float*)d_in[2];
  const float* W  = (const float*)d_in[3];
  const float* bm = (const float*)d_in[4];
  const float* mu = (const float*)d_in[5];
  const float* lv = (const float*)d_in[6];
  float* out = (float*)d_out;
  char* ws = (char*)d_ws;
  (void)in_sizes; (void)n_in; (void)out_size; (void)ws_size; // need ~74.2 MB ws

  float* emp    = (float*)(ws + 0x0000000);
  float* cvec   = (float*)(ws + 0x0200000);
  float* muT    = (float*)(ws + 0x0210000);
  float* ivT    = (float*)(ws + 0x0214000);
  float* logdet = (float*)(ws + 0x0218000);
  u16*   Ap     = (u16*)  (ws + 0x0400000);
  u16*   Mc     = (u16*)  (ws + 0x4400000);
  float* sc1    = (float*)(ws + 0x4600000);
  u16*   M2     = (u16*)  (ws + 0x4601000);
  float* sc2    = (float*)(ws + 0x4681000);
  u16*   M3     = (u16*)  (ws + 0x4682000);
  float* sc3    = (float*)(ws + 0x46A2000);
  u16*   M4     = (u16*)  (ws + 0x46A3000);
  float* sc4    = (float*)(ws + 0x46AB000);

  k_prep <<<1, 64, 0, stream>>>(mu, lv, muT, ivT, logdet);
  k_emis <<<2048, 256, 0, stream>>>(Y, muT, ivT, logdet, emp, cvec);
  k_trans<<<dim3(64, 64), 256, 0, stream>>>(X, W, bm, emp, Ap);
  // stage C: 256 chunks x 32 matrices (chunk 0 skips t=0; em_0 enters via alpha0)
  k_scan <<<256, 256, 0, stream>>>(Ap, 32, 1, (const float*)nullptr, Mc, sc1);
  // combine levels, fan-in 4: 256 -> 64 -> 16 -> 4
  k_scan <<<64, 256, 0, stream>>>(Mc, 4, 0, sc1, M2, sc2);
  k_scan <<<16, 256, 0, stream>>>(M2, 4, 0, sc2, M3, sc3);
  k_scan <<<4,  256, 0, stream>>>(M3, 4, 0, sc3, M4, sc4);
  k_final<<<1, 256, 0, stream>>>(il, emp, cvec, M4, sc4, 4, out);
}

// Round 3
// 237.122 us; speedup vs baseline: 1.8807x; 1.4325x over previous
//
#include <hip/hip_runtime.h>
#include <hip/hip_bf16.h>

// TVHMM forward log-likelihood, chunk-parallel linear-domain operator scan.
// R2: k_scan occupancy fix (1024 chunks, in-place tree) + v_dot2_f32_bf16.
// ws layout (bytes), total ~68 MB:
//   0x0000000 emp    [8192][64] f32
//   0x0200000 cvec   [8192] f32
//   0x0210000 muT / 0x0214000 ivT / 0x0218000 logdet
//   0x0220000 sc1[1024][4] 0x0224000 sc2[256][4] 0x0225000 sc3[64][4]
//   0x0226000 sc4[16][4]   0x0227000 sc5[4][4]
//   0x0400000 Ap [8192][64][64] bf16 -- scan tree folds IN PLACE:
//     L0: 1024 blocks x 8 mats -> slot 8b; L1: 256 x4 -> slot 32b;
//     L2: 64 x4 -> 128b; L3: 16 x4 -> 512b; L4: 4 x4 -> 2048b; final reads stride 2048.

typedef unsigned int u32;
typedef unsigned short u16;

#define T_LEN 8192

typedef __attribute__((ext_vector_type(8))) short bf16x8;
typedef __attribute__((ext_vector_type(4))) float f32x4;

__device__ __forceinline__ float bflo(u32 u){ return __uint_as_float(u << 16); }
__device__ __forceinline__ float bfhi(u32 u){ return __uint_as_float(u & 0xffff0000u); }
__device__ __forceinline__ u32 f2bf(float x){
  u32 b = __float_as_uint(x);
  return (b + 0x7fffu + ((b >> 16) & 1u)) >> 16;
}
__device__ __forceinline__ u32 pack2bf(float a, float b){
  return f2bf(a) | (f2bf(b) << 16);
}

#if defined(__has_builtin)
#if __has_builtin(__builtin_amdgcn_fdot2_f32_bf16)
#define HAVE_DOT2 1
#endif
#endif

#if HAVE_DOT2
typedef __attribute__((ext_vector_type(2))) __bf16 bf16v2;
__device__ __forceinline__ float dot2bf(u32 a, u32 b, float c){
  return __builtin_amdgcn_fdot2_f32_bf16(
      __builtin_bit_cast(bf16v2, a), __builtin_bit_cast(bf16v2, b), c, false);
}
#else
__device__ __forceinline__ float dot2bf(u32 a, u32 b, float c){
  return fmaf(bfhi(a), bfhi(b), fmaf(bflo(a), bflo(b), c));
}
#endif

// ---------------------------------------------------------------- k_prep
__global__ __launch_bounds__(64) void k_prep(
    const float* __restrict__ mu, const float* __restrict__ lvu,
    float* __restrict__ muT, float* __restrict__ ivT, float* __restrict__ logdet)
{
  const int k = threadIdx.x;
  float ld = 0.f;
  for (int d = 0; d < 64; ++d){
    float lv = fminf(fmaxf(lvu[k*64 + d], -6.f), 6.f);
    ld += lv;
    muT[d*64 + k] = mu[k*64 + d];
    ivT[d*64 + k] = __expf(-lv);
  }
  logdet[k] = ld;
}

// ---------------------------------------------------------------- k_emis
__global__ __launch_bounds__(256) void k_emis(
    const float* __restrict__ Y, const float* __restrict__ muT,
    const float* __restrict__ ivT, const float* __restrict__ logdet,
    float* __restrict__ emp, float* __restrict__ cvec)
{
  const int w = threadIdx.x >> 6, k = threadIdx.x & 63;
  const int t = blockIdx.x * 4 + w;
  float y = Y[(size_t)t*64 + k];
  float quad = 0.f;
  #pragma unroll 8
  for (int d = 0; d < 64; ++d){
    float yd = __shfl(y, d, 64);
    float df = yd - muT[d*64 + k];
    quad = fmaf(df*df, ivT[d*64 + k], quad);
  }
  float le = -0.5f*(117.6241322f + logdet[k] + quad);   // 64*log(2pi)
  float m = le;
  #pragma unroll
  for (int off = 1; off < 64; off <<= 1) m = fmaxf(m, __shfl_xor(m, off, 64));
  emp[(size_t)t*64 + k] = __expf(le - m);
  if (k == 0) cvec[t] = m;
}

// ---------------------------------------------------------------- k_trans (MFMA)
__global__ __launch_bounds__(256) void k_trans(
    const float* __restrict__ X, const float* __restrict__ W,
    const float* __restrict__ bmat, const float* __restrict__ emp,
    u16* __restrict__ Ap)
{
  __shared__ __align__(16) u16 Xs[128*128];   // 32 KB, XOR-swizzled rows
  __shared__ __align__(16) u16 Ws[64*128];    // 16 KB
  const int tid = threadIdx.x;
  const int t0 = blockIdx.x * 128;
  const int i  = blockIdx.y;

  { // stage: f32 -> bf16, swizzle byte ^= (row&7)<<4
    const float4* xs = (const float4*)(X + (size_t)t0 * 128);
    #pragma unroll
    for (int u = 0; u < 16; ++u){
      int f = u*256 + tid;
      float4 v = xs[f];
      int row = f >> 5, c = f & 31;
      int byte = (row*256 + c*8) ^ ((row & 7) << 4);
      *(uint2*)((char*)Xs + byte) = make_uint2(pack2bf(v.x, v.y), pack2bf(v.z, v.w));
    }
    const float4* wsrc = (const float4*)(W + (size_t)i * 8192);
    #pragma unroll
    for (int u = 0; u < 8; ++u){
      int f = u*256 + tid;
      float4 v = wsrc[f];
      int row = f >> 5, c = f & 31;
      int byte = (row*256 + c*8) ^ ((row & 7) << 4);
      *(uint2*)((char*)Ws + byte) = make_uint2(pack2bf(v.x, v.y), pack2bf(v.z, v.w));
    }
  }
  __syncthreads();

  const int lane = tid & 63, w = tid >> 6;
  const int lr = lane & 15, lg = lane >> 4;

  f32x4 acc[2][4] = {};
  #pragma unroll
  for (int kg = 0; kg < 4; ++kg){
    const int kbyte = kg*64 + lg*16;
    bf16x8 a[2], b[4];
    #pragma unroll
    for (int mt = 0; mt < 2; ++mt){
      int row = w*32 + mt*16 + lr;
      a[mt] = *(const bf16x8*)((const char*)Xs + ((row*256 + kbyte) ^ ((row&7)<<4)));
    }
    #pragma unroll
    for (int nt = 0; nt < 4; ++nt){
      int row = nt*16 + lr;
      b[nt] = *(const bf16x8*)((const char*)Ws + ((row*256 + kbyte) ^ ((row&7)<<4)));
    }
    #pragma unroll
    for (int mt = 0; mt < 2; ++mt)
      #pragma unroll
      for (int nt = 0; nt < 4; ++nt)
        acc[mt][nt] = __builtin_amdgcn_mfma_f32_16x16x32_bf16(a[mt], b[nt], acc[mt][nt], 0, 0, 0);
  }

  float bv[4];
  #pragma unroll
  for (int nt = 0; nt < 4; ++nt) bv[nt] = bmat[i*64 + nt*16 + lr];

  #pragma unroll
  for (int mt = 0; mt < 2; ++mt){
    #pragma unroll
    for (int reg = 0; reg < 4; ++reg){
      const int t = t0 + w*32 + mt*16 + lg*4 + reg;
      float v0 = acc[mt][0][reg] + bv[0];
      float v1 = acc[mt][1][reg] + bv[1];
      float v2 = acc[mt][2][reg] + bv[2];
      float v3 = acc[mt][3][reg] + bv[3];
      float mx = fmaxf(fmaxf(v0,v1), fmaxf(v2,v3));
      #pragma unroll
      for (int off = 1; off < 16; off <<= 1) mx = fmaxf(mx, __shfl_xor(mx, off, 64));
      float e0 = __expf(v0-mx), e1 = __expf(v1-mx), e2 = __expf(v2-mx), e3 = __expf(v3-mx);
      float sum = e0 + e1 + e2 + e3;
      #pragma unroll
      for (int off = 1; off < 16; off <<= 1) sum += __shfl_xor(sum, off, 64);
      float inv = 1.0f / sum;
      const float* er = emp + (size_t)t*64;
      u16* op = Ap + (size_t)t*4096 + i*64;
      op[ 0 + lr] = (u16)f2bf(e0*inv*er[ 0 + lr]);
      op[16 + lr] = (u16)f2bf(e1*inv*er[16 + lr]);
      op[32 + lr] = (u16)f2bf(e2*inv*er[32 + lr]);
      op[48 + lr] = (u16)f2bf(e3*inv*er[48 + lr]);
    }
  }
}

// ---------------------------------------------------------------- k_scan
// Fold per_wg matrices (input index c -> slot c*mstride in `mats`, each 4096
// elems) into one: M <- rescale(M * Op). Writes result IN PLACE to slot
// (blockIdx.x*per_wg)*mstride (its own first-input slot, read-before-write).
// Wave w owns rows 16w..16w+15; lane (r,g): row 16w+r, cols 16g..16g+15 as
// 8 col-pair u32. Operand in LDS row-pair packed, XOR-swizzled, dbuf.
__global__ __launch_bounds__(256) void k_scan(
    u16* mats, int mstride, int per_wg, int skip0,
    const float* __restrict__ in_sc, float* __restrict__ out_sc)
{
  __shared__ u32 Apk[2][32][64];   // 16 KB
  const int tid = threadIdx.x;
  const int lane = tid & 63, w = tid >> 6;
  const int r = lane & 15, g = lane >> 4;
  int c0 = blockIdx.x * per_wg, cnt = per_wg;
  const size_t out_slot = (size_t)c0 * mstride;
  if (blockIdx.x == 0){ c0 += skip0; cnt -= skip0; }

  u32 M[8];
  {
    const uint4* mp0 = (const uint4*)(mats + ((size_t)c0*mstride << 12) + ((w*16 + r) << 6) + (g << 4));
    uint4 a = mp0[0], b = mp0[1];
    M[0]=a.x; M[1]=a.y; M[2]=a.z; M[3]=a.w;
    M[4]=b.x; M[5]=b.y; M[6]=b.z; M[7]=b.w;
  }
  float S = in_sc ? in_sc[c0*4 + w] : 0.0f;

  const int lp = tid >> 3, c8 = tid & 7;
  auto STAGE = [&](int buf, const u16* src){
    const uint4 A = *(const uint4*)(src + lp*128 + c8*8);
    const uint4 B = *(const uint4*)(src + lp*128 + 64 + c8*8);
    uint4 o0, o1;
    o0.x = (A.x & 0xffffu) | (B.x << 16);
    o0.y = (A.x >> 16)     | (B.x & 0xffff0000u);
    o0.z = (A.y & 0xffffu) | (B.y << 16);
    o0.w = (A.y >> 16)     | (B.y & 0xffff0000u);
    o1.x = (A.z & 0xffffu) | (B.z << 16);
    o1.y = (A.z >> 16)     | (B.z & 0xffff0000u);
    o1.z = (A.w & 0xffffu) | (B.w << 16);
    o1.w = (A.w >> 16)     | (B.w & 0xffff0000u);
    const int s = lp & 7;
    *(uint4*)&Apk[buf][lp][((2*c8    ) ^ s) << 2] = o0;
    *(uint4*)&Apk[buf][lp][((2*c8 + 1) ^ s) << 2] = o1;
  };

  if (cnt > 1) STAGE(0, mats + ((size_t)(c0+1)*mstride << 12));
  __syncthreads();
  int cur = 0;
  for (int kk = 1; kk < cnt; ++kk){
    if (kk + 1 < cnt) STAGE(cur ^ 1, mats + ((size_t)(c0 + kk + 1)*mstride << 12));

    if (in_sc){ // fold Op's row-block scales into M's columns
      const float* sp = in_sc + (size_t)(c0 + kk)*4;
      float s0=sp[0], s1=sp[1], s2=sp[2], s3=sp[3];
      float sm = fmaxf(fmaxf(s0,s1), fmaxf(s2,s3));
      float se = __expf(sp[g] - sm);
      S += sm;
      #pragma unroll
      for (int q = 0; q < 8; ++q)
        M[q] = pack2bf(bflo(M[q])*se, bfhi(M[q])*se);
    }

    float acc[16];
    #pragma unroll
    for (int c = 0; c < 16; ++c) acc[c] = 0.f;
    const u32* Ab = &Apk[cur][0][0];
    #pragma unroll
    for (int p = 0; p < 32; ++p){
      u32 mp = __shfl(M[p & 7], r + ((p >> 3) << 4), 64);  // (M[row][2p], M[row][2p+1])
      const u32* Ar = Ab + p*64;
      #pragma unroll
      for (int k4 = 0; k4 < 4; ++k4){
        uint4 av = *(const uint4*)(Ar + ((((g<<2) + k4) ^ (p & 7)) << 2));
        acc[k4*4+0] = dot2bf(mp, av.x, acc[k4*4+0]);
        acc[k4*4+1] = dot2bf(mp, av.y, acc[k4*4+1]);
        acc[k4*4+2] = dot2bf(mp, av.z, acc[k4*4+2]);
        acc[k4*4+3] = dot2bf(mp, av.w, acc[k4*4+3]);
      }
    }
    float mx = acc[0];
    #pragma unroll
    for (int c = 1; c < 16; ++c) mx = fmaxf(mx, acc[c]);
    #pragma unroll
    for (int off = 1; off < 64; off <<= 1) mx = fmaxf(mx, __shfl_xor(mx, off, 64));
    float inv = 1.0f / mx;
    S += __logf(mx);
    #pragma unroll
    for (int q = 0; q < 8; ++q)
      M[q] = pack2bf(acc[2*q]*inv, acc[2*q+1]*inv);
    cur ^= 1;
    __syncthreads();
  }
  {
    uint4* outp = (uint4*)(mats + (out_slot << 12) + ((w*16 + r) << 6) + (g << 4));
    uint4 a, b;
    a.x=M[0]; a.y=M[1]; a.z=M[2]; a.w=M[3];
    b.x=M[4]; b.y=M[5]; b.z=M[6]; b.w=M[7];
    outp[0] = a; outp[1] = b;
    if (lane == 0) out_sc[blockIdx.x*4 + w] = S;
  }
}

// ---------------------------------------------------------------- k_final
__global__ __launch_bounds__(256) void k_final(
    const float* __restrict__ init_logits, const float* __restrict__ emp,
    const float* __restrict__ cvec, const u16* __restrict__ Mfin, int mstride,
    const float* __restrict__ scfin, int nmat, float* __restrict__ out)
{
  __shared__ float wsum[4];
  const int tid = threadIdx.x;
  float part = 0.f;
  for (int t = tid; t < T_LEN; t += 256) part += cvec[t];
  #pragma unroll
  for (int off = 1; off < 64; off <<= 1) part += __shfl_xor(part, off, 64);
  if ((tid & 63) == 0) wsum[tid >> 6] = part;
  __syncthreads();
  if (tid >= 64) return;
  const float csum = wsum[0] + wsum[1] + wsum[2] + wsum[3];
  const int k = tid;
  float ilv = init_logits[k];
  float m = ilv;
  #pragma unroll
  for (int off = 1; off < 64; off <<= 1) m = fmaxf(m, __shfl_xor(m, off, 64));
  float e = __expf(ilv - m);
  float s = e;
  #pragma unroll
  for (int off = 1; off < 64; off <<= 1) s += __shfl_xor(s, off, 64);
  float alpha = (e / s) * emp[k];
  float S = 0.f;
  for (int d = 0; d < nmat; ++d){
    const float* sp = scfin + d*4;
    float sm = fmaxf(fmaxf(sp[0], sp[1]), fmaxf(sp[2], sp[3]));
    alpha *= __expf(sp[k >> 4] - sm);
    S += sm;
    const u16* Mp = Mfin + ((size_t)d*mstride << 12);
    float an = 0.f;
    for (int i2 = 0; i2 < 64; ++i2){
      float av = __shfl(alpha, i2, 64);
      an = fmaf(av, __uint_as_float(((u32)Mp[i2*64 + k]) << 16), an);
    }
    float mx = an;
    #pragma unroll
    for (int off = 1; off < 64; off <<= 1) mx = fmaxf(mx, __shfl_xor(mx, off, 64));
    alpha = an / mx;
    S += __logf(mx);
  }
  float tot = alpha;
  #pragma unroll
  for (int off = 1; off < 64; off <<= 1) tot += __shfl_xor(tot, off, 64);
  if (k == 0) out[0] = __logf(tot) + S + csum;
}

// ---------------------------------------------------------------- launch
extern "C" void kernel_launch(void* const* d_in, const int* in_sizes, int n_in,
                              void* d_out, int out_size, void* d_ws, size_t ws_size,
                              hipStream_t stream)
{
  const float* X  = (const float*)d_in[0];
  const float* Y  = (const float*)d_in[1];
  const float* il = (const float*)d_in[2];
  const float* W  = (const float*)d_in[3];
  const float* bm = (const float*)d_in[4];
  const float* mu = (const float*)d_in[5];
  const float* lv = (const float*)d_in[6];
  float* out = (float*)d_out;
  char* ws = (char*)d_ws;
  (void)in_sizes; (void)n_in; (void)out_size; (void)ws_size; // need ~68 MB ws

  float* emp    = (float*)(ws + 0x0000000);
  float* cvec   = (float*)(ws + 0x0200000);
  float* muT    = (float*)(ws + 0x0210000);
  float* ivT    = (float*)(ws + 0x0214000);
  float* logdet = (float*)(ws + 0x0218000);
  float* sc1    = (float*)(ws + 0x0220000);
  float* sc2    = (float*)(ws + 0x0224000);
  float* sc3    = (float*)(ws + 0x0225000);
  float* sc4    = (float*)(ws + 0x0226000);
  float* sc5    = (float*)(ws + 0x0227000);
  u16*   Ap     = (u16*)  (ws + 0x0400000);

  k_prep <<<1, 64, 0, stream>>>(mu, lv, muT, ivT, logdet);
  k_emis <<<2048, 256, 0, stream>>>(Y, muT, ivT, logdet, emp, cvec);
  k_trans<<<dim3(64, 64), 256, 0, stream>>>(X, W, bm, emp, Ap);
  // in-place scan tree over Ap
  k_scan <<<1024, 256, 0, stream>>>(Ap,   1, 8, 1, (const float*)nullptr, sc1);
  k_scan <<<256,  256, 0, stream>>>(Ap,   8, 4, 0, sc1, sc2);
  k_scan <<<64,   256, 0, stream>>>(Ap,  32, 4, 0, sc2, sc3);
  k_scan <<<16,   256, 0, stream>>>(Ap, 128, 4, 0, sc3, sc4);
  k_scan <<<4,    256, 0, stream>>>(Ap, 512, 4, 0, sc4, sc5);
  k_final<<<1, 256, 0, stream>>>(il, emp, cvec, Ap, 2048, sc5, 4, out);
}

// Round 4
// 196.212 us; speedup vs baseline: 2.2729x; 1.2085x over previous
//
#include <hip/hip_runtime.h>
#include <hip/hip_bf16.h>

// TVHMM forward log-likelihood, chunk-parallel linear-domain operator scan.
// R3: k_scan rewritten as MFMA in transposed space (state = B-frags in regs,
//     Op^T gathered from pair-packed stride-272 LDS); k_trans epilogue
//     LDS-bounce for coalesced 128B global writes.
// ws layout unchanged (~68 MB): emp/cvec/muT/ivT/logdet/sc1..sc5/Ap in-place tree.

typedef unsigned int u32;
typedef unsigned short u16;

#define T_LEN 8192

typedef __attribute__((ext_vector_type(8))) short bf16x8;
typedef __attribute__((ext_vector_type(4))) float f32x4;

__device__ __forceinline__ float bflo(u32 u){ return __uint_as_float(u << 16); }
__device__ __forceinline__ float bfhi(u32 u){ return __uint_as_float(u & 0xffff0000u); }
__device__ __forceinline__ u32 f2bf(float x){
  u32 b = __float_as_uint(x);
  return (b + 0x7fffu + ((b >> 16) & 1u)) >> 16;
}
__device__ __forceinline__ u32 pack2bf(float a, float b){
  return f2bf(a) | (f2bf(b) << 16);
}

// ---------------------------------------------------------------- k_prep
__global__ __launch_bounds__(64) void k_prep(
    const float* __restrict__ mu, const float* __restrict__ lvu,
    float* __restrict__ muT, float* __restrict__ ivT, float* __restrict__ logdet)
{
  const int k = threadIdx.x;
  float ld = 0.f;
  for (int d = 0; d < 64; ++d){
    float lv = fminf(fmaxf(lvu[k*64 + d], -6.f), 6.f);
    ld += lv;
    muT[d*64 + k] = mu[k*64 + d];
    ivT[d*64 + k] = __expf(-lv);
  }
  logdet[k] = ld;
}

// ---------------------------------------------------------------- k_emis
__global__ __launch_bounds__(256) void k_emis(
    const float* __restrict__ Y, const float* __restrict__ muT,
    const float* __restrict__ ivT, const float* __restrict__ logdet,
    float* __restrict__ emp, float* __restrict__ cvec)
{
  const int w = threadIdx.x >> 6, k = threadIdx.x & 63;
  const int t = blockIdx.x * 4 + w;
  float y = Y[(size_t)t*64 + k];
  float quad = 0.f;
  #pragma unroll 8
  for (int d = 0; d < 64; ++d){
    float yd = __shfl(y, d, 64);
    float df = yd - muT[d*64 + k];
    quad = fmaf(df*df, ivT[d*64 + k], quad);
  }
  float le = -0.5f*(117.6241322f + logdet[k] + quad);   // 64*log(2pi)
  float m = le;
  #pragma unroll
  for (int off = 1; off < 64; off <<= 1) m = fmaxf(m, __shfl_xor(m, off, 64));
  emp[(size_t)t*64 + k] = __expf(le - m);
  if (k == 0) cvec[t] = m;
}

// ---------------------------------------------------------------- k_trans (MFMA)
// Block (bt, i): 128 t-rows x 64 j for source state i. logits = b + X.W;
// row-softmax over j; * em'; bf16. Epilogue bounces through LDS (reuse Xs)
// so global writes are 128B-contiguous dwordx4 runs.
__global__ __launch_bounds__(256) void k_trans(
    const float* __restrict__ X, const float* __restrict__ W,
    const float* __restrict__ bmat, const float* __restrict__ emp,
    u16* __restrict__ Ap)
{
  __shared__ __align__(16) u16 Xs[128*128];   // 32 KB, XOR-swizzled rows
  __shared__ __align__(16) u16 Ws[64*128];    // 16 KB
  const int tid = threadIdx.x;
  const int t0 = blockIdx.x * 128;
  const int i  = blockIdx.y;

  { // stage: f32 -> bf16, swizzle byte ^= (row&7)<<4
    const float4* xs = (const float4*)(X + (size_t)t0 * 128);
    #pragma unroll
    for (int u = 0; u < 16; ++u){
      int f = u*256 + tid;
      float4 v = xs[f];
      int row = f >> 5, c = f & 31;
      int byte = (row*256 + c*8) ^ ((row & 7) << 4);
      *(uint2*)((char*)Xs + byte) = make_uint2(pack2bf(v.x, v.y), pack2bf(v.z, v.w));
    }
    const float4* wsrc = (const float4*)(W + (size_t)i * 8192);
    #pragma unroll
    for (int u = 0; u < 8; ++u){
      int f = u*256 + tid;
      float4 v = wsrc[f];
      int row = f >> 5, c = f & 31;
      int byte = (row*256 + c*8) ^ ((row & 7) << 4);
      *(uint2*)((char*)Ws + byte) = make_uint2(pack2bf(v.x, v.y), pack2bf(v.z, v.w));
    }
  }
  __syncthreads();

  const int lane = tid & 63, w = tid >> 6;
  const int lr = lane & 15, lg = lane >> 4;

  f32x4 acc[2][4] = {};
  #pragma unroll
  for (int kg = 0; kg < 4; ++kg){
    const int kbyte = kg*64 + lg*16;
    bf16x8 a[2], b[4];
    #pragma unroll
    for (int mt = 0; mt < 2; ++mt){
      int row = w*32 + mt*16 + lr;
      a[mt] = *(const bf16x8*)((const char*)Xs + ((row*256 + kbyte) ^ ((row&7)<<4)));
    }
    #pragma unroll
    for (int nt = 0; nt < 4; ++nt){
      int row = nt*16 + lr;
      b[nt] = *(const bf16x8*)((const char*)Ws + ((row*256 + kbyte) ^ ((row&7)<<4)));
    }
    #pragma unroll
    for (int mt = 0; mt < 2; ++mt)
      #pragma unroll
      for (int nt = 0; nt < 4; ++nt)
        acc[mt][nt] = __builtin_amdgcn_mfma_f32_16x16x32_bf16(a[mt], b[nt], acc[mt][nt], 0, 0, 0);
  }

  float bv[4];
  #pragma unroll
  for (int nt = 0; nt < 4; ++nt) bv[nt] = bmat[i*64 + nt*16 + lr];

  __syncthreads();                 // Xs no longer needed as operand; reuse
  u16* Ct = Xs;                    // [128][64] u16, row-XOR-swizzled

  #pragma unroll
  for (int mt = 0; mt < 2; ++mt){
    #pragma unroll
    for (int reg = 0; reg < 4; ++reg){
      const int row = w*32 + mt*16 + lg*4 + reg;
      const int t = t0 + row;
      float v0 = acc[mt][0][reg] + bv[0];
      float v1 = acc[mt][1][reg] + bv[1];
      float v2 = acc[mt][2][reg] + bv[2];
      float v3 = acc[mt][3][reg] + bv[3];
      float mx = fmaxf(fmaxf(v0,v1), fmaxf(v2,v3));
      #pragma unroll
      for (int off = 1; off < 16; off <<= 1) mx = fmaxf(mx, __shfl_xor(mx, off, 64));
      float e0 = __expf(v0-mx), e1 = __expf(v1-mx), e2 = __expf(v2-mx), e3 = __expf(v3-mx);
      float sum = e0 + e1 + e2 + e3;
      #pragma unroll
      for (int off = 1; off < 16; off <<= 1) sum += __shfl_xor(sum, off, 64);
      float inv = 1.0f / sum;
      const float* er = emp + (size_t)t*64;
      const int sw = (row & 7) << 4;
      *(u16*)((char*)Ct + row*128 + ((( 0 + lr)*2) ^ sw)) = (u16)f2bf(e0*inv*er[ 0 + lr]);
      *(u16*)((char*)Ct + row*128 + (((16 + lr)*2) ^ sw)) = (u16)f2bf(e1*inv*er[16 + lr]);
      *(u16*)((char*)Ct + row*128 + (((32 + lr)*2) ^ sw)) = (u16)f2bf(e2*inv*er[32 + lr]);
      *(u16*)((char*)Ct + row*128 + (((48 + lr)*2) ^ sw)) = (u16)f2bf(e3*inv*er[48 + lr]);
    }
  }
  __syncthreads();
  #pragma unroll
  for (int q = 0; q < 4; ++q){
    const int f = tid*4 + q;         // uint4 index 0..1023
    const int row = f >> 3, c = f & 7;
    uint4 v = *(const uint4*)((const char*)Ct + row*128 + ((c*16) ^ ((row & 7) << 4)));
    *(uint4*)(Ap + (size_t)(t0 + row)*4096 + (size_t)i*64 + c*8) = v;
  }
}

// ---------------------------------------------------------------- k_scan (MFMA)
// Fold per_wg matrices (slot c*mstride, 4096 elems each) into one, in place.
// Transposed space: MT <- Op^T * MT.
//  - state: B-frags in regs; wave w owns M rows [16w,16w+16): lane (r16,oct)
//    holds Bf[kt] = M[16w+r16][kt*32+oct*8 .. +8] bf16.
//  - Op^T A-frags gathered from LDS pair-packed [ip][j] u32
//    (= Op[2ip][j], Op[2ip+1][j]), row stride 68 dwords (272 B) => all
//    gathers 2-way max bank aliasing (free).
//  - C (col=lane&15=r16) -> next B-frags via cvt-pack + 16 __shfl + select.
__global__ __launch_bounds__(256) void k_scan(
    u16* mats, int mstride, int per_wg, int skip0,
    const float* __restrict__ in_sc, float* __restrict__ out_sc)
{
  __shared__ u32 Apk[2][32*68];   // 2 x 8704 B, double-buffered
  const int tid = threadIdx.x;
  const int lane = tid & 63, w = tid >> 6;
  const int r16 = lane & 15, oct = lane >> 4;
  int c0 = blockIdx.x * per_wg, cnt = per_wg;
  const size_t out_slot = (size_t)c0 * mstride;
  if (blockIdx.x == 0){ c0 += skip0; cnt -= skip0; }

  bf16x8 Bf[2];
  {
    const u16* m0 = mats + ((size_t)c0*mstride << 12) + (w*16 + r16)*64 + oct*8;
    Bf[0] = *(const bf16x8*)(m0);
    Bf[1] = *(const bf16x8*)(m0 + 32);
  }
  float S = in_sc ? in_sc[c0*4 + w] : 0.0f;

  const int lp = tid >> 3, c8 = tid & 7;
  auto STAGE = [&](int buf, const u16* src){
    const uint4 A = *(const uint4*)(src + lp*128 + c8*8);        // row 2lp
    const uint4 B = *(const uint4*)(src + lp*128 + 64 + c8*8);   // row 2lp+1
    uint4 o0, o1;
    o0.x = (A.x & 0xffffu) | (B.x << 16);
    o0.y = (A.x >> 16)     | (B.x & 0xffff0000u);
    o0.z = (A.y & 0xffffu) | (B.y << 16);
    o0.w = (A.y >> 16)     | (B.y & 0xffff0000u);
    o1.x = (A.z & 0xffffu) | (B.z << 16);
    o1.y = (A.z >> 16)     | (B.z & 0xffff0000u);
    o1.z = (A.w & 0xffffu) | (B.w << 16);
    o1.w = (A.w >> 16)     | (B.w & 0xffff0000u);
    u32* dst = &Apk[buf][lp*68 + c8*8];
    *(uint4*)(dst)     = o0;
    *(uint4*)(dst + 4) = o1;
  };

  if (cnt > 1) STAGE(0, mats + ((size_t)(c0+1)*mstride << 12));
  __syncthreads();
  int cur = 0;
  for (int kk = 1; kk < cnt; ++kk){
    if (kk + 1 < cnt) STAGE(cur ^ 1, mats + ((size_t)(c0 + kk + 1)*mstride << 12));

    if (in_sc){ // fold Op's row-block scales into state columns (i-blocks)
      const float* sp = in_sc + (size_t)(c0 + kk)*4;
      float s0=sp[0], s1=sp[1], s2=sp[2], s3=sp[3];
      float sm = fmaxf(fmaxf(s0,s1), fmaxf(s2,s3));
      S += sm;
      #pragma unroll
      for (int kt = 0; kt < 2; ++kt){
        float slo = (kt == 0) ? s0 : s2;
        float shi = (kt == 0) ? s1 : s3;
        float se = __expf(((oct >> 1) ? shi : slo) - sm);
        uint4 bv4 = __builtin_bit_cast(uint4, Bf[kt]);
        bv4.x = pack2bf(bflo(bv4.x)*se, bfhi(bv4.x)*se);
        bv4.y = pack2bf(bflo(bv4.y)*se, bfhi(bv4.y)*se);
        bv4.z = pack2bf(bflo(bv4.z)*se, bfhi(bv4.z)*se);
        bv4.w = pack2bf(bflo(bv4.w)*se, bfhi(bv4.w)*se);
        Bf[kt] = __builtin_bit_cast(bf16x8, bv4);
      }
    }

    f32x4 acc[4] = {};
    const u32* Ab = &Apk[cur][0];
    #pragma unroll
    for (int kt = 0; kt < 2; ++kt){
      const u32* gb = Ab + (kt*16 + oct*4)*68 + r16;
      #pragma unroll
      for (int jt = 0; jt < 4; ++jt){
        const u32* g = gb + jt*16;
        uint4 av = make_uint4(g[0], g[68], g[136], g[204]);
        acc[jt] = __builtin_amdgcn_mfma_f32_16x16x32_bf16(
            __builtin_bit_cast(bf16x8, av), Bf[kt], acc[jt], 0, 0, 0);
      }
    }

    // wave-wide rescale
    float mx = acc[0][0];
    #pragma unroll
    for (int jt = 0; jt < 4; ++jt)
      #pragma unroll
      for (int q = 0; q < 4; ++q) mx = fmaxf(mx, acc[jt][q]);
    #pragma unroll
    for (int off = 1; off < 64; off <<= 1) mx = fmaxf(mx, __shfl_xor(mx, off, 64));
    float inv = 1.0f / mx;
    S += __logf(mx);

    // pack C to bf16 pairs: p0[jt] = rows (oct*4+0,+1), p1[jt] = (+2,+3) of col r16
    u32 p0[4], p1[4];
    #pragma unroll
    for (int jt = 0; jt < 4; ++jt){
      p0[jt] = pack2bf(acc[jt][0]*inv, acc[jt][1]*inv);
      p1[jt] = pack2bf(acc[jt][2]*inv, acc[jt][3]*inv);
    }
    // redistribute to next-step B-frags (verified lane mapping):
    // target (r16,oct) frag kt: j = kt*32+oct*8+e from tile jt=2kt+(oct>>1),
    // source lanes s0 = r16+32*(oct&1) (e<4), s1 = s0+16 (e>=4).
    const int s0l = r16 + 32*(oct & 1), s1l = s0l + 16;
    const bool hi = (oct >> 1) != 0;
    #pragma unroll
    for (int kt = 0; kt < 2; ++kt){
      u32 a0 = __shfl(p0[2*kt],   s0l, 64), a1 = __shfl(p1[2*kt],   s0l, 64);
      u32 a2 = __shfl(p0[2*kt],   s1l, 64), a3 = __shfl(p1[2*kt],   s1l, 64);
      u32 b0 = __shfl(p0[2*kt+1], s0l, 64), b1 = __shfl(p1[2*kt+1], s0l, 64);
      u32 b2 = __shfl(p0[2*kt+1], s1l, 64), b3 = __shfl(p1[2*kt+1], s1l, 64);
      uint4 nb;
      nb.x = hi ? b0 : a0;
      nb.y = hi ? b1 : a1;
      nb.z = hi ? b2 : a2;
      nb.w = hi ? b3 : a3;
      Bf[kt] = __builtin_bit_cast(bf16x8, nb);
    }
    cur ^= 1;
    __syncthreads();
  }
  {
    u16* outp = mats + (out_slot << 12) + (w*16 + r16)*64 + oct*8;
    *(bf16x8*)(outp)      = Bf[0];
    *(bf16x8*)(outp + 32) = Bf[1];
    if (lane == 0) out_sc[blockIdx.x*4 + w] = S;
  }
}

// ---------------------------------------------------------------- k_final
__global__ __launch_bounds__(256) void k_final(
    const float* __restrict__ init_logits, const float* __restrict__ emp,
    const float* __restrict__ cvec, const u16* __restrict__ Mfin, int mstride,
    const float* __restrict__ scfin, int nmat, float* __restrict__ out)
{
  __shared__ float wsum[4];
  const int tid = threadIdx.x;
  float part = 0.f;
  for (int t = tid; t < T_LEN; t += 256) part += cvec[t];
  #pragma unroll
  for (int off = 1; off < 64; off <<= 1) part += __shfl_xor(part, off, 64);
  if ((tid & 63) == 0) wsum[tid >> 6] = part;
  __syncthreads();
  if (tid >= 64) return;
  const float csum = wsum[0] + wsum[1] + wsum[2] + wsum[3];
  const int k = tid;
  float ilv = init_logits[k];
  float m = ilv;
  #pragma unroll
  for (int off = 1; off < 64; off <<= 1) m = fmaxf(m, __shfl_xor(m, off, 64));
  float e = __expf(ilv - m);
  float s = e;
  #pragma unroll
  for (int off = 1; off < 64; off <<= 1) s += __shfl_xor(s, off, 64);
  float alpha = (e / s) * emp[k];
  float S = 0.f;
  for (int d = 0; d < nmat; ++d){
    const float* sp = scfin + d*4;
    float sm = fmaxf(fmaxf(sp[0], sp[1]), fmaxf(sp[2], sp[3]));
    alpha *= __expf(sp[k >> 4] - sm);
    S += sm;
    const u16* Mp = Mfin + ((size_t)d*mstride << 12);
    float an = 0.f;
    for (int i2 = 0; i2 < 64; ++i2){
      float av = __shfl(alpha, i2, 64);
      an = fmaf(av, __uint_as_float(((u32)Mp[i2*64 + k]) << 16), an);
    }
    float mx = an;
    #pragma unroll
    for (int off = 1; off < 64; off <<= 1) mx = fmaxf(mx, __shfl_xor(mx, off, 64));
    alpha = an / mx;
    S += __logf(mx);
  }
  float tot = alpha;
  #pragma unroll
  for (int off = 1; off < 64; off <<= 1) tot += __shfl_xor(tot, off, 64);
  if (k == 0) out[0] = __logf(tot) + S + csum;
}

// ---------------------------------------------------------------- launch
extern "C" void kernel_launch(void* const* d_in, const int* in_sizes, int n_in,
                              void* d_out, int out_size, void* d_ws, size_t ws_size,
                              hipStream_t stream)
{
  const float* X  = (const float*)d_in[0];
  const float* Y  = (const float*)d_in[1];
  const float* il = (const float*)d_in[2];
  const float* W  = (const float*)d_in[3];
  const float* bm = (const float*)d_in[4];
  const float* mu = (const float*)d_in[5];
  const float* lv = (const float*)d_in[6];
  float* out = (float*)d_out;
  char* ws = (char*)d_ws;
  (void)in_sizes; (void)n_in; (void)out_size; (void)ws_size; // need ~68 MB ws

  float* emp    = (float*)(ws + 0x0000000);
  float* cvec   = (float*)(ws + 0x0200000);
  float* muT    = (float*)(ws + 0x0210000);
  float* ivT    = (float*)(ws + 0x0214000);
  float* logdet = (float*)(ws + 0x0218000);
  float* sc1    = (float*)(ws + 0x0220000);
  float* sc2    = (float*)(ws + 0x0224000);
  float* sc3    = (float*)(ws + 0x0225000);
  float* sc4    = (float*)(ws + 0x0226000);
  float* sc5    = (float*)(ws + 0x0227000);
  u16*   Ap     = (u16*)  (ws + 0x0400000);

  k_prep <<<1, 64, 0, stream>>>(mu, lv, muT, ivT, logdet);
  k_emis <<<2048, 256, 0, stream>>>(Y, muT, ivT, logdet, emp, cvec);
  k_trans<<<dim3(64, 64), 256, 0, stream>>>(X, W, bm, emp, Ap);
  // in-place scan tree over Ap
  k_scan <<<1024, 256, 0, stream>>>(Ap,   1, 8, 1, (const float*)nullptr, sc1);
  k_scan <<<256,  256, 0, stream>>>(Ap,   8, 4, 0, sc1, sc2);
  k_scan <<<64,   256, 0, stream>>>(Ap,  32, 4, 0, sc2, sc3);
  k_scan <<<16,   256, 0, stream>>>(Ap, 128, 4, 0, sc3, sc4);
  k_scan <<<4,    256, 0, stream>>>(Ap, 512, 4, 0, sc4, sc5);
  k_final<<<1, 256, 0, stream>>>(il, emp, cvec, Ap, 2048, sc5, 4, out);
}